// Round 9
// baseline (71.753 us; speedup 1.0000x reference)
//
#include <hip/hip_runtime.h>
#include <hip/hip_bf16.h>

typedef __attribute__((ext_vector_type(4))) float f32x4;
typedef __attribute__((ext_vector_type(16))) float f32x16;
typedef __attribute__((ext_vector_type(4))) float f4;
typedef __attribute__((ext_vector_type(8))) short bf16x8;
typedef __attribute__((ext_vector_type(4))) short s16x4;
typedef __attribute__((ext_vector_type(4))) unsigned u32x4;

#define T_LEN 2048
#define SPAD 72
// log2(e)/64: folds BOTH 1/8 scale factors and the exp->exp2 conversion.
#define QSCALE 0.022542110013890054f

__device__ inline short f2bf(float f) {
  unsigned u = __builtin_bit_cast(unsigned, f);
  return (short)((u + 0x7fffu + ((u >> 16) & 1u)) >> 16);
}

// ---------------------------------------------------------------------------
// prep_t: fp32 -> bf16 per-head transpose. sel=0: Q (linear [t][c]),
// PRE-SCALED by log2(e)/64. sel=1: K (tiled [stile][row][c ^ ((row&7)<<3)]).
// grid = 2048, block = 256.
// ---------------------------------------------------------------------------
__global__ __launch_bounds__(256) void prep_t(const float* __restrict__ qkv,
                                              short* __restrict__ qt,
                                              short* __restrict__ kt) {
  __shared__ float tile[64][65];
  const int bid = blockIdx.x;
  const int tch = bid & 31;
  const int head = (bid >> 5) & 31;
  const int sel = bid >> 10;
  const int b = head >> 3, h = head & 7;
  const float* src = qkv + ((size_t)b * 1536 + sel * 512 + h * 64) * T_LEN + tch * 64;
  short* dst = (sel ? kt : qt) + (size_t)head * T_LEN * 64 + (size_t)tch * 64 * 64;
  const int tid = threadIdx.x;
  const float sc = sel ? 1.0f : QSCALE;

  for (int e = tid; e < 4096; e += 256) {
    int c = e >> 6, t = e & 63;
    tile[c][t] = src[(size_t)c * T_LEN + t];
  }
  __syncthreads();
  for (int e = tid; e < 2048; e += 256) {
    int t = e >> 5, c2 = (e & 31) * 2;
    unsigned lo = (unsigned short)f2bf(tile[c2][t] * sc);
    unsigned hi = (unsigned short)f2bf(tile[c2 + 1][t] * sc);
    int cdst = sel ? (c2 ^ ((t & 7) << 3)) : c2;
    *(unsigned*)&dst[t * 64 + cdst] = lo | (hi << 16);
  }
}

// ---------------------------------------------------------------------------
// prep_v: fp32 -> bf16 V, tiled per head [stile][c][s ^ ((c&7)<<3)].
// grid = 4096, block = 256.
// ---------------------------------------------------------------------------
__global__ __launch_bounds__(256) void prep_v(const float* __restrict__ qkv,
                                              short* __restrict__ v_out) {
  int id = blockIdx.x * 256 + threadIdx.x;
  int s4 = id & 15;
  int c = (id >> 4) & 63;
  int stile = (id >> 10) & 31;
  int head = id >> 15;
  int b = head >> 3, h = head & 7;
  const float* src =
      qkv + ((size_t)b * 1536 + 1024 + h * 64 + c) * T_LEN + stile * 64 + s4 * 4;
  f4 s = *(const f4*)src;
  s16x4 o;
#pragma unroll
  for (int j = 0; j < 4; ++j) o[j] = f2bf(s[j]);
  size_t dsts = (((size_t)head * 32 + stile) * 64 + c) * 64 + ((s4 * 4) ^ ((c & 7) << 3));
  *(s16x4*)&v_out[dsts] = o;
}

// ---------------------------------------------------------------------------
// attn8: swapped-QK^T 32x32 flash attention, no-max softmax (exp2 domain),
// in-register P pack (cvt_pk + permlane32_swap), triple-buffered LDS K/V via
// global_load_lds, and a 2-tile software pipeline: QK^T(i+1) MFMAs issue in
// the same block as softmax+PV(i), so matrix/LDS pipes run under the exp
// VALU phase (T15). grid = 512 = qblk(16) x head(32); block = 256.
// ---------------------------------------------------------------------------
__global__ __launch_bounds__(256, 2) void attn8(const short* __restrict__ Qt,
                                                const short* __restrict__ Kt,
                                                const short* __restrict__ Vb,
                                                float* __restrict__ out) {
  __shared__ short KV[3][2][4096];  // [buf][0=K,1=V][64x64 swizzled tile]

  const int bid = blockIdx.x;
  const int head = bid & 31;  // head pinned to one XCD's L2
  const int qblk = bid >> 5;

  const int tid = threadIdx.x;
  const int wave = tid >> 6;
  const int lane = tid & 63;
  const int l31 = lane & 31;
  const int hi = lane >> 5;

  const int t0 = qblk * 128 + wave * 32;  // this wave's 32 query rows

  const short* Qh = Qt + (size_t)head * 131072;
  const short* Kh = Kt + (size_t)head * 131072;
  const short* Vh = Vb + (size_t)head * 131072;
  float* O = out + (size_t)head * 131072;

  auto stage = [&](int buf, int it) {
#pragma unroll
    for (int j = 0; j < 4; ++j) {
      const int chunk = wave * 4 + j;  // 0-7 = K, 8-15 = V
      const short* g = (chunk < 8 ? Kh : Vh) + it * 4096 + (chunk & 7) * 512 + lane * 8;
      short* l = &KV[buf][chunk >> 3][(chunk & 7) * 512];
      __builtin_amdgcn_global_load_lds((const __attribute__((address_space(1))) void*)g,
                                       (__attribute__((address_space(3))) void*)l,
                                       16, 0, 0);
    }
  };

  // Q (B operand): lane holds B[k=c=ck*16+hi*8+j][col=t=l31]
  bf16x8 aq[4];
#pragma unroll
  for (int ck = 0; ck < 4; ++ck)
    aq[ck] = *(const bf16x8*)&Qh[(size_t)(t0 + l31) * 64 + ck * 16 + hi * 8];

  float l_lane = 0.f;
  f32x16 o_acc[2];
#pragma unroll
  for (int j = 0; j < 16; ++j) { o_acc[0][j] = 0.f; o_acc[1][j] = 0.f; }

  // S^T = K Q^T for one 64-s tile (exp2 domain already; Q pre-scaled)
  auto qk = [&](f32x16& sa, f32x16& sb, int buf) {
#pragma unroll
    for (int j = 0; j < 16; ++j) { sa[j] = 0.f; sb[j] = 0.f; }
#pragma unroll
    for (int ck = 0; ck < 4; ++ck) {
      const int r0 = l31;
      const bf16x8 k0 = *(const bf16x8*)&KV[buf][0][r0 * 64 + ((ck * 16 + hi * 8) ^ ((r0 & 7) << 3))];
      sa = __builtin_amdgcn_mfma_f32_32x32x16_bf16(k0, aq[ck], sa, 0, 0, 0);
      const int r1 = 32 + l31;
      const bf16x8 k1 = *(const bf16x8*)&KV[buf][0][r1 * 64 + ((ck * 16 + hi * 8) ^ ((r1 & 7) << 3))];
      sb = __builtin_amdgcn_mfma_f32_32x32x16_bf16(k1, aq[ck], sb, 0, 0, 0);
    }
  };

  // softmax (p = exp2(s)) + in-register pack + PV for one tile
  auto soft_pv = [&](const f32x16& sa, const f32x16& sb, int buf) {
    float ps0 = 0.f, ps1 = 0.f, ps2 = 0.f, ps3 = 0.f;
    bf16x8 pf[4];
    const f32x16* sv[2] = {&sa, &sb};
#pragma unroll
    for (int sbk = 0; sbk < 2; ++sbk) {
      float p[16];
#pragma unroll
      for (int j = 0; j < 16; ++j) p[j] = exp2f((*sv[sbk])[j]);
      ps0 += p[0] + p[4] + p[8] + p[12];
      ps1 += p[1] + p[5] + p[9] + p[13];
      ps2 += p[2] + p[6] + p[10] + p[14];
      ps3 += p[3] + p[7] + p[11] + p[15];
      unsigned w0, w1, w2, w3, w4, w5, w6, w7;
      asm("v_cvt_pk_bf16_f32 %0, %1, %2" : "=v"(w0) : "v"(p[0]), "v"(p[1]));
      asm("v_cvt_pk_bf16_f32 %0, %1, %2" : "=v"(w1) : "v"(p[2]), "v"(p[3]));
      asm("v_cvt_pk_bf16_f32 %0, %1, %2" : "=v"(w2) : "v"(p[4]), "v"(p[5]));
      asm("v_cvt_pk_bf16_f32 %0, %1, %2" : "=v"(w3) : "v"(p[6]), "v"(p[7]));
      asm("v_cvt_pk_bf16_f32 %0, %1, %2" : "=v"(w4) : "v"(p[8]), "v"(p[9]));
      asm("v_cvt_pk_bf16_f32 %0, %1, %2" : "=v"(w5) : "v"(p[10]), "v"(p[11]));
      asm("v_cvt_pk_bf16_f32 %0, %1, %2" : "=v"(w6) : "v"(p[12]), "v"(p[13]));
      asm("v_cvt_pk_bf16_f32 %0, %1, %2" : "=v"(w7) : "v"(p[14]), "v"(p[15]));
      // vdst.high <-> vsrc.low; vdst = low-s word: one swap fills two words
      asm("v_permlane32_swap_b32 %0, %1" : "+v"(w0), "+v"(w2));
      asm("v_permlane32_swap_b32 %0, %1" : "+v"(w1), "+v"(w3));
      asm("v_permlane32_swap_b32 %0, %1" : "+v"(w4), "+v"(w6));
      asm("v_permlane32_swap_b32 %0, %1" : "+v"(w5), "+v"(w7));
      u32x4 fe = {w0, w1, w2, w3};
      u32x4 fo = {w4, w5, w6, w7};
      pf[sbk * 2] = __builtin_bit_cast(bf16x8, fe);
      pf[sbk * 2 + 1] = __builtin_bit_cast(bf16x8, fo);
    }
    l_lane += (ps0 + ps1) + (ps2 + ps3);
#pragma unroll
    for (int sc = 0; sc < 4; ++sc) {
#pragma unroll
      for (int ct = 0; ct < 2; ++ct) {
        const int rc = ct * 32 + l31;
        const bf16x8 vf = *(const bf16x8*)&KV[buf][1][rc * 64 + ((sc * 16 + hi * 8) ^ ((rc & 7) << 3))];
        o_acc[ct] = __builtin_amdgcn_mfma_f32_32x32x16_bf16(vf, pf[sc], o_acc[ct], 0, 0, 0);
      }
    }
  };

  // ---- prologue: tiles 0 and 1 staged; S(0) computed ----
  stage(0, 0);
  stage(1, 1);
  __syncthreads();

  f32x16 sE0, sE1, sO0, sO1;
  qk(sE0, sE1, 0);

  int b0 = 0, b1 = 1, b2 = 2;  // b0 = tile i, b1 = tile i+1, b2 = stage target
  for (int ip = 0; ip < 16; ++ip) {
    const int i = ip * 2;
    // even iter i: pipeline QK(i+1) under softmax+PV(i)
    if (i + 2 < 32) stage(b2, i + 2);
    qk(sO0, sO1, b1);        // tile i+1 scores (independent MFMA/LDS stream)
    soft_pv(sE0, sE1, b0);   // tile i exp/pack/PV (VALU/trans stream)
    __syncthreads();         // stage(i+2) landed; buf b0 now reusable
    // odd iter i+1
    if (i + 3 < 32) stage(b0, i + 3);
    if (i + 2 < 32) qk(sE0, sE1, b2);  // tile i+2
    soft_pv(sO0, sO1, b1);             // tile i+1
    __syncthreads();
    // advance two tiles: (b0,b1,b2) <- (b2,b0,b1)
    const int nb0 = b2, nb1 = b0, nb2 = b1;
    b0 = nb0; b1 = nb1; b2 = nb2;
  }

  // ---- epilogue: combine lane halves' l, write O[c][t] directly ----
  const float l = l_lane + __shfl_xor(l_lane, 32, 64);
  const float rl = 1.0f / l;
#pragma unroll
  for (int ct = 0; ct < 2; ++ct)
#pragma unroll
    for (int j = 0; j < 16; ++j) {
      const int c = ct * 32 + (j & 3) + 8 * (j >> 2) + 4 * hi;
      O[(size_t)c * T_LEN + t0 + l31] = o_acc[ct][j] * rl;
    }
}

// ---------------------------------------------------------------------------
// Fallback (round-1 kernel) if ws_size is too small for the bf16 prep buffers.
// ---------------------------------------------------------------------------
__global__ __launch_bounds__(256) void attn_fwd(const float* __restrict__ qkv,
                                                float* __restrict__ out) {
  __shared__ short KtS[64][SPAD];
  __shared__ short VtS[64][SPAD];
  __shared__ short PbS[4][16][SPAD];

  const int bid = blockIdx.x;
  const int qt = bid & 31;
  const int head = bid >> 5;
  const int b = head >> 3, h = head & 7;

  const size_t base = ((size_t)b * 1536 + h * 64) * T_LEN;
  const float* Q = qkv + base;
  const float* K = qkv + base + (size_t)512 * T_LEN;
  const float* V = qkv + base + (size_t)1024 * T_LEN;
  float* O = out + ((size_t)b * 512 + h * 64) * T_LEN;

  const int tid = threadIdx.x;
  const int wave = tid >> 6;
  const int lane = tid & 63;
  const int l15 = lane & 15;
  const int l4 = lane >> 4;
  const int t0 = qt * 64 + wave * 16;

  bf16x8 aq[2];
#pragma unroll
  for (int kk = 0; kk < 2; ++kk)
#pragma unroll
    for (int j = 0; j < 8; ++j) {
      int c = kk * 32 + l4 * 8 + j;
      aq[kk][j] = f2bf(Q[(size_t)c * T_LEN + t0 + l15]);
    }

  float m_run[4], l_run[4];
  f32x4 o_acc[4];
#pragma unroll
  for (int r = 0; r < 4; ++r) { m_run[r] = -1e30f; l_run[r] = 0.f; }
#pragma unroll
  for (int n = 0; n < 4; ++n) o_acc[n] = (f32x4){0.f, 0.f, 0.f, 0.f};

  const float inv64 = 0.015625f;

  for (int s0 = 0; s0 < T_LEN; s0 += 64) {
    __syncthreads();
    for (int e = tid; e < 4096; e += 256) {
      int c = e >> 6, s = e & 63;
      KtS[s][c] = f2bf(K[(size_t)c * T_LEN + s0 + s]);
      VtS[c][s] = f2bf(V[(size_t)c * T_LEN + s0 + s]);
    }
    __syncthreads();

    f32x4 sacc[4];
#pragma unroll
    for (int n = 0; n < 4; ++n) {
      const bf16x8 bk0 = *(const bf16x8*)&KtS[16 * n + l15][l4 * 8];
      const bf16x8 bk1 = *(const bf16x8*)&KtS[16 * n + l15][32 + l4 * 8];
      f32x4 z = (f32x4){0.f, 0.f, 0.f, 0.f};
      z = __builtin_amdgcn_mfma_f32_16x16x32_bf16(aq[0], bk0, z, 0, 0, 0);
      z = __builtin_amdgcn_mfma_f32_16x16x32_bf16(aq[1], bk1, z, 0, 0, 0);
      sacc[n] = z;
    }

#pragma unroll
    for (int r = 0; r < 4; ++r) {
      float mx = fmaxf(fmaxf(sacc[0][r], sacc[1][r]),
                       fmaxf(sacc[2][r], sacc[3][r])) * inv64;
#pragma unroll
      for (int off = 8; off >= 1; off >>= 1)
        mx = fmaxf(mx, __shfl_xor(mx, off, 64));
      const float m_new = fmaxf(m_run[r], mx);
      const float alpha = __expf(m_run[r] - m_new);
      float psum = 0.f;
#pragma unroll
      for (int n = 0; n < 4; ++n) {
        float p = __expf(sacc[n][r] * inv64 - m_new);
        psum += p;
        PbS[wave][l4 * 4 + r][16 * n + l15] = f2bf(p);
      }
#pragma unroll
      for (int off = 8; off >= 1; off >>= 1)
        psum += __shfl_xor(psum, off, 64);
      l_run[r] = l_run[r] * alpha + psum;
      m_run[r] = m_new;
#pragma unroll
      for (int n = 0; n < 4; ++n) o_acc[n][r] *= alpha;
    }

    const bf16x8 ap0 = *(const bf16x8*)&PbS[wave][l15][l4 * 8];
    const bf16x8 ap1 = *(const bf16x8*)&PbS[wave][l15][32 + l4 * 8];
#pragma unroll
    for (int n = 0; n < 4; ++n) {
      const bf16x8 bv0 = *(const bf16x8*)&VtS[16 * n + l15][l4 * 8];
      const bf16x8 bv1 = *(const bf16x8*)&VtS[16 * n + l15][32 + l4 * 8];
      o_acc[n] = __builtin_amdgcn_mfma_f32_16x16x32_bf16(ap0, bv0, o_acc[n], 0, 0, 0);
      o_acc[n] = __builtin_amdgcn_mfma_f32_16x16x32_bf16(ap1, bv1, o_acc[n], 0, 0, 0);
    }
  }

#pragma unroll
  for (int n = 0; n < 4; ++n)
#pragma unroll
    for (int r = 0; r < 4; ++r) {
      const int c = 16 * n + l15;
      const int t = t0 + l4 * 4 + r;
      O[(size_t)c * T_LEN + t] = o_acc[n][r] / l_run[r];
    }
}

extern "C" void kernel_launch(void* const* d_in, const int* in_sizes, int n_in,
                              void* d_out, int out_size, void* d_ws, size_t ws_size,
                              hipStream_t stream) {
  const float* qkv = (const float*)d_in[0];
  float* out = (float*)d_out;
  const size_t per_buf = (size_t)32 * T_LEN * 64;
  const size_t need = per_buf * 3 * sizeof(short);
  if (ws_size >= need) {
    short* qt = (short*)d_ws;
    short* kt = qt + per_buf;
    short* vb = kt + per_buf;
    hipLaunchKernelGGL(prep_t, dim3(2048), dim3(256), 0, stream, qkv, qt, kt);
    hipLaunchKernelGGL(prep_v, dim3(4096), dim3(256), 0, stream, qkv, vb);
    hipLaunchKernelGGL(attn8, dim3(512), dim3(256), 0, stream, qt, kt, vb, out);
  } else {
    hipLaunchKernelGGL(attn_fwd, dim3(1024), dim3(256), 0, stream, qkv, out);
  }
}

// Round 10
// 59.096 us; speedup vs baseline: 1.2142x; 1.2142x over previous
//
#include <hip/hip_runtime.h>
#include <hip/hip_bf16.h>

typedef __attribute__((ext_vector_type(4))) float f32x4;
typedef __attribute__((ext_vector_type(16))) float f32x16;
typedef __attribute__((ext_vector_type(4))) float f4;
typedef __attribute__((ext_vector_type(8))) short bf16x8;
typedef __attribute__((ext_vector_type(4))) short s16x4;
typedef __attribute__((ext_vector_type(4))) unsigned u32x4;

#define T_LEN 2048
#define SPAD 72
// log2(e)/64: folds BOTH 1/8 scale factors and the exp->exp2 conversion.
#define QSCALE 0.022542110013890054f

__device__ inline short f2bf(float f) {
  unsigned u = __builtin_bit_cast(unsigned, f);
  return (short)((u + 0x7fffu + ((u >> 16) & 1u)) >> 16);
}

// ---------------------------------------------------------------------------
// prep_t: fp32 -> bf16 per-head transpose. sel=0: Q (linear [t][c]),
// PRE-SCALED by log2(e)/64. sel=1: K (tiled [stile][row][c ^ ((row&7)<<3)]).
// grid = 2048, block = 256.
// ---------------------------------------------------------------------------
__global__ __launch_bounds__(256) void prep_t(const float* __restrict__ qkv,
                                              short* __restrict__ qt,
                                              short* __restrict__ kt) {
  __shared__ float tile[64][65];
  const int bid = blockIdx.x;
  const int tch = bid & 31;
  const int head = (bid >> 5) & 31;
  const int sel = bid >> 10;
  const int b = head >> 3, h = head & 7;
  const float* src = qkv + ((size_t)b * 1536 + sel * 512 + h * 64) * T_LEN + tch * 64;
  short* dst = (sel ? kt : qt) + (size_t)head * T_LEN * 64 + (size_t)tch * 64 * 64;
  const int tid = threadIdx.x;
  const float sc = sel ? 1.0f : QSCALE;

  for (int e = tid; e < 4096; e += 256) {
    int c = e >> 6, t = e & 63;
    tile[c][t] = src[(size_t)c * T_LEN + t];
  }
  __syncthreads();
  for (int e = tid; e < 2048; e += 256) {
    int t = e >> 5, c2 = (e & 31) * 2;
    unsigned lo = (unsigned short)f2bf(tile[c2][t] * sc);
    unsigned hi = (unsigned short)f2bf(tile[c2 + 1][t] * sc);
    int cdst = sel ? (c2 ^ ((t & 7) << 3)) : c2;
    *(unsigned*)&dst[t * 64 + cdst] = lo | (hi << 16);
  }
}

// ---------------------------------------------------------------------------
// prep_v: fp32 -> bf16 V, tiled per head [stile][c][s ^ ((c&7)<<3)].
// grid = 4096, block = 256.
// ---------------------------------------------------------------------------
__global__ __launch_bounds__(256) void prep_v(const float* __restrict__ qkv,
                                              short* __restrict__ v_out) {
  int id = blockIdx.x * 256 + threadIdx.x;
  int s4 = id & 15;
  int c = (id >> 4) & 63;
  int stile = (id >> 10) & 31;
  int head = id >> 15;
  int b = head >> 3, h = head & 7;
  const float* src =
      qkv + ((size_t)b * 1536 + 1024 + h * 64 + c) * T_LEN + stile * 64 + s4 * 4;
  f4 s = *(const f4*)src;
  s16x4 o;
#pragma unroll
  for (int j = 0; j < 4; ++j) o[j] = f2bf(s[j]);
  size_t dsts = (((size_t)head * 32 + stile) * 64 + c) * 64 + ((s4 * 4) ^ ((c & 7) << 3));
  *(s16x4*)&v_out[dsts] = o;
}

// ---------------------------------------------------------------------------
// attn9: attn7 structure (2-buffer, 1 barrier/tile -- explicit pipeline of
// round 9 REVERTED: cross-wave drift at 2 waves/SIMD already overlaps pipes).
// Changes vs attn7: (1) bare v_exp_f32 via __builtin_amdgcn_exp2f (domain
// s in [-2,2], no denormal fixup needed -- OCML exp2f is ~5 instrs);
// (2) unroll-by-2 with compile-time buf so all LDS/stage addresses are
// loop-invariant. grid = 512 = qblk(16) x head(32); block = 256.
// ---------------------------------------------------------------------------
__global__ __launch_bounds__(256, 2) void attn9(const short* __restrict__ Qt,
                                                const short* __restrict__ Kt,
                                                const short* __restrict__ Vb,
                                                float* __restrict__ out) {
  __shared__ short KV[2][2][4096];  // [buf][0=K,1=V][64x64 swizzled tile]

  const int bid = blockIdx.x;
  const int head = bid & 31;  // head pinned to one XCD's L2
  const int qblk = bid >> 5;

  const int tid = threadIdx.x;
  const int wave = tid >> 6;
  const int lane = tid & 63;
  const int l31 = lane & 31;
  const int hi = lane >> 5;

  const int t0 = qblk * 128 + wave * 32;  // this wave's 32 query rows

  const short* Qh = Qt + (size_t)head * 131072;
  const short* Kh = Kt + (size_t)head * 131072;
  const short* Vh = Vb + (size_t)head * 131072;
  float* O = out + (size_t)head * 131072;

  auto stage = [&](int buf, int it) {
#pragma unroll
    for (int j = 0; j < 4; ++j) {
      const int chunk = wave * 4 + j;  // 0-7 = K, 8-15 = V
      const short* g = (chunk < 8 ? Kh : Vh) + it * 4096 + (chunk & 7) * 512 + lane * 8;
      short* l = &KV[buf][chunk >> 3][(chunk & 7) * 512];
      __builtin_amdgcn_global_load_lds((const __attribute__((address_space(1))) void*)g,
                                       (__attribute__((address_space(3))) void*)l,
                                       16, 0, 0);
    }
  };

  // Q (B operand): lane holds B[k=c=ck*16+hi*8+j][col=t=l31]
  bf16x8 aq[4];
#pragma unroll
  for (int ck = 0; ck < 4; ++ck)
    aq[ck] = *(const bf16x8*)&Qh[(size_t)(t0 + l31) * 64 + ck * 16 + hi * 8];

  float l_lane = 0.f;
  f32x16 o_acc[2];
#pragma unroll
  for (int j = 0; j < 16; ++j) { o_acc[0][j] = 0.f; o_acc[1][j] = 0.f; }

  // one full tile: S^T = K Q^T -> p = exp2(s) -> in-reg pack -> O^T += V P^T
  auto tile_body = [&](int buf) {
    f32x16 s0, s1;
#pragma unroll
    for (int j = 0; j < 16; ++j) { s0[j] = 0.f; s1[j] = 0.f; }
#pragma unroll
    for (int ck = 0; ck < 4; ++ck) {
      const int r0 = l31;
      const bf16x8 k0 = *(const bf16x8*)&KV[buf][0][r0 * 64 + ((ck * 16 + hi * 8) ^ ((r0 & 7) << 3))];
      s0 = __builtin_amdgcn_mfma_f32_32x32x16_bf16(k0, aq[ck], s0, 0, 0, 0);
      const int r1 = 32 + l31;
      const bf16x8 k1 = *(const bf16x8*)&KV[buf][0][r1 * 64 + ((ck * 16 + hi * 8) ^ ((r1 & 7) << 3))];
      s1 = __builtin_amdgcn_mfma_f32_32x32x16_bf16(k1, aq[ck], s1, 0, 0, 0);
    }

    float ps0 = 0.f, ps1 = 0.f, ps2 = 0.f, ps3 = 0.f;
    bf16x8 pf[4];
    const f32x16* sv[2] = {&s0, &s1};
#pragma unroll
    for (int sbk = 0; sbk < 2; ++sbk) {
      float p[16];
#pragma unroll
      for (int j = 0; j < 16; ++j) p[j] = __builtin_amdgcn_exp2f((*sv[sbk])[j]);
      ps0 += p[0] + p[4] + p[8] + p[12];
      ps1 += p[1] + p[5] + p[9] + p[13];
      ps2 += p[2] + p[6] + p[10] + p[14];
      ps3 += p[3] + p[7] + p[11] + p[15];
      unsigned w0, w1, w2, w3, w4, w5, w6, w7;
      asm("v_cvt_pk_bf16_f32 %0, %1, %2" : "=v"(w0) : "v"(p[0]), "v"(p[1]));
      asm("v_cvt_pk_bf16_f32 %0, %1, %2" : "=v"(w1) : "v"(p[2]), "v"(p[3]));
      asm("v_cvt_pk_bf16_f32 %0, %1, %2" : "=v"(w2) : "v"(p[4]), "v"(p[5]));
      asm("v_cvt_pk_bf16_f32 %0, %1, %2" : "=v"(w3) : "v"(p[6]), "v"(p[7]));
      asm("v_cvt_pk_bf16_f32 %0, %1, %2" : "=v"(w4) : "v"(p[8]), "v"(p[9]));
      asm("v_cvt_pk_bf16_f32 %0, %1, %2" : "=v"(w5) : "v"(p[10]), "v"(p[11]));
      asm("v_cvt_pk_bf16_f32 %0, %1, %2" : "=v"(w6) : "v"(p[12]), "v"(p[13]));
      asm("v_cvt_pk_bf16_f32 %0, %1, %2" : "=v"(w7) : "v"(p[14]), "v"(p[15]));
      // vdst.high <-> vsrc.low; vdst = low-s word: one swap fills two words
      asm("v_permlane32_swap_b32 %0, %1" : "+v"(w0), "+v"(w2));
      asm("v_permlane32_swap_b32 %0, %1" : "+v"(w1), "+v"(w3));
      asm("v_permlane32_swap_b32 %0, %1" : "+v"(w4), "+v"(w6));
      asm("v_permlane32_swap_b32 %0, %1" : "+v"(w5), "+v"(w7));
      u32x4 fe = {w0, w1, w2, w3};
      u32x4 fo = {w4, w5, w6, w7};
      pf[sbk * 2] = __builtin_bit_cast(bf16x8, fe);
      pf[sbk * 2 + 1] = __builtin_bit_cast(bf16x8, fo);
    }
    l_lane += (ps0 + ps1) + (ps2 + ps3);

#pragma unroll
    for (int sc = 0; sc < 4; ++sc) {
#pragma unroll
      for (int ct = 0; ct < 2; ++ct) {
        const int rc = ct * 32 + l31;
        const bf16x8 vf = *(const bf16x8*)&KV[buf][1][rc * 64 + ((sc * 16 + hi * 8) ^ ((rc & 7) << 3))];
        o_acc[ct] = __builtin_amdgcn_mfma_f32_32x32x16_bf16(vf, pf[sc], o_acc[ct], 0, 0, 0);
      }
    }
  };

  stage(0, 0);
  __syncthreads();

  // unroll-by-2: buf is a compile-time constant in each half
  for (int itp = 0; itp < 16; ++itp) {
    const int it = itp * 2;
    stage(1, it + 1);                 // prefetch into buf1 under compute(buf0)
    tile_body(0);
    __syncthreads();                  // prefetch landed; buf0 reusable
    if (it + 2 < 32) stage(0, it + 2);
    tile_body(1);
    __syncthreads();
  }

  // ---- epilogue: combine lane halves' l, write O[c][t] directly ----
  const float l = l_lane + __shfl_xor(l_lane, 32, 64);
  const float rl = 1.0f / l;
#pragma unroll
  for (int ct = 0; ct < 2; ++ct)
#pragma unroll
    for (int j = 0; j < 16; ++j) {
      const int c = ct * 32 + (j & 3) + 8 * (j >> 2) + 4 * hi;
      O[(size_t)c * T_LEN + t0 + l31] = o_acc[ct][j] * rl;
    }
}

// ---------------------------------------------------------------------------
// Fallback (round-1 kernel) if ws_size is too small for the bf16 prep buffers.
// ---------------------------------------------------------------------------
__global__ __launch_bounds__(256) void attn_fwd(const float* __restrict__ qkv,
                                                float* __restrict__ out) {
  __shared__ short KtS[64][SPAD];
  __shared__ short VtS[64][SPAD];
  __shared__ short PbS[4][16][SPAD];

  const int bid = blockIdx.x;
  const int qt = bid & 31;
  const int head = bid >> 5;
  const int b = head >> 3, h = head & 7;

  const size_t base = ((size_t)b * 1536 + h * 64) * T_LEN;
  const float* Q = qkv + base;
  const float* K = qkv + base + (size_t)512 * T_LEN;
  const float* V = qkv + base + (size_t)1024 * T_LEN;
  float* O = out + ((size_t)b * 512 + h * 64) * T_LEN;

  const int tid = threadIdx.x;
  const int wave = tid >> 6;
  const int lane = tid & 63;
  const int l15 = lane & 15;
  const int l4 = lane >> 4;
  const int t0 = qt * 64 + wave * 16;

  bf16x8 aq[2];
#pragma unroll
  for (int kk = 0; kk < 2; ++kk)
#pragma unroll
    for (int j = 0; j < 8; ++j) {
      int c = kk * 32 + l4 * 8 + j;
      aq[kk][j] = f2bf(Q[(size_t)c * T_LEN + t0 + l15]);
    }

  float m_run[4], l_run[4];
  f32x4 o_acc[4];
#pragma unroll
  for (int r = 0; r < 4; ++r) { m_run[r] = -1e30f; l_run[r] = 0.f; }
#pragma unroll
  for (int n = 0; n < 4; ++n) o_acc[n] = (f32x4){0.f, 0.f, 0.f, 0.f};

  const float inv64 = 0.015625f;

  for (int s0 = 0; s0 < T_LEN; s0 += 64) {
    __syncthreads();
    for (int e = tid; e < 4096; e += 256) {
      int c = e >> 6, s = e & 63;
      KtS[s][c] = f2bf(K[(size_t)c * T_LEN + s0 + s]);
      VtS[c][s] = f2bf(V[(size_t)c * T_LEN + s0 + s]);
    }
    __syncthreads();

    f32x4 sacc[4];
#pragma unroll
    for (int n = 0; n < 4; ++n) {
      const bf16x8 bk0 = *(const bf16x8*)&KtS[16 * n + l15][l4 * 8];
      const bf16x8 bk1 = *(const bf16x8*)&KtS[16 * n + l15][32 + l4 * 8];
      f32x4 z = (f32x4){0.f, 0.f, 0.f, 0.f};
      z = __builtin_amdgcn_mfma_f32_16x16x32_bf16(aq[0], bk0, z, 0, 0, 0);
      z = __builtin_amdgcn_mfma_f32_16x16x32_bf16(aq[1], bk1, z, 0, 0, 0);
      sacc[n] = z;
    }

#pragma unroll
    for (int r = 0; r < 4; ++r) {
      float mx = fmaxf(fmaxf(sacc[0][r], sacc[1][r]),
                       fmaxf(sacc[2][r], sacc[3][r])) * inv64;
#pragma unroll
      for (int off = 8; off >= 1; off >>= 1)
        mx = fmaxf(mx, __shfl_xor(mx, off, 64));
      const float m_new = fmaxf(m_run[r], mx);
      const float alpha = __expf(m_run[r] - m_new);
      float psum = 0.f;
#pragma unroll
      for (int n = 0; n < 4; ++n) {
        float p = __expf(sacc[n][r] * inv64 - m_new);
        psum += p;
        PbS[wave][l4 * 4 + r][16 * n + l15] = f2bf(p);
      }
#pragma unroll
      for (int off = 8; off >= 1; off >>= 1)
        psum += __shfl_xor(psum, off, 64);
      l_run[r] = l_run[r] * alpha + psum;
      m_run[r] = m_new;
#pragma unroll
      for (int n = 0; n < 4; ++n) o_acc[n][r] *= alpha;
    }

    const bf16x8 ap0 = *(const bf16x8*)&PbS[wave][l15][l4 * 8];
    const bf16x8 ap1 = *(const bf16x8*)&PbS[wave][l15][32 + l4 * 8];
#pragma unroll
    for (int n = 0; n < 4; ++n) {
      const bf16x8 bv0 = *(const bf16x8*)&VtS[16 * n + l15][l4 * 8];
      const bf16x8 bv1 = *(const bf16x8*)&VtS[16 * n + l15][32 + l4 * 8];
      o_acc[n] = __builtin_amdgcn_mfma_f32_16x16x32_bf16(ap0, bv0, o_acc[n], 0, 0, 0);
      o_acc[n] = __builtin_amdgcn_mfma_f32_16x16x32_bf16(ap1, bv1, o_acc[n], 0, 0, 0);
    }
  }

#pragma unroll
  for (int n = 0; n < 4; ++n)
#pragma unroll
    for (int r = 0; r < 4; ++r) {
      const int c = 16 * n + l15;
      const int t = t0 + l4 * 4 + r;
      O[(size_t)c * T_LEN + t] = o_acc[n][r] / l_run[r];
    }
}

extern "C" void kernel_launch(void* const* d_in, const int* in_sizes, int n_in,
                              void* d_out, int out_size, void* d_ws, size_t ws_size,
                              hipStream_t stream) {
  const float* qkv = (const float*)d_in[0];
  float* out = (float*)d_out;
  const size_t per_buf = (size_t)32 * T_LEN * 64;
  const size_t need = per_buf * 3 * sizeof(short);
  if (ws_size >= need) {
    short* qt = (short*)d_ws;
    short* kt = qt + per_buf;
    short* vb = kt + per_buf;
    hipLaunchKernelGGL(prep_t, dim3(2048), dim3(256), 0, stream, qkv, qt, kt);
    hipLaunchKernelGGL(prep_v, dim3(4096), dim3(256), 0, stream, qkv, vb);
    hipLaunchKernelGGL(attn9, dim3(512), dim3(256), 0, stream, qt, kt, vb, out);
  } else {
    hipLaunchKernelGGL(attn_fwd, dim3(1024), dim3(256), 0, stream, qkv, out);
  }
}